// Round 15
// baseline (185.116 us; speedup 1.0000x reference)
//
#include <hip/hip_runtime.h>
#include <hip/hip_fp8.h>
#include <math.h>

// Problem dims
#define S_   8
#define B_   16
#define D_   10
#define N_   32
#define E_   300
#define H_   128
#define G4_  512
#define SDIM_ 96
#define MID_ 256
#define TOT_ 528

#define GP_  514   // gates LDS row pad (f32): 4*514%32=8 -> 2-way max on write

typedef unsigned short u16;
typedef unsigned int u32;
typedef unsigned char u8;
typedef unsigned long long u64;
typedef __attribute__((ext_vector_type(8))) short short8;
typedef __attribute__((ext_vector_type(4))) float f32x4;

// round-to-nearest-even f32 -> bf16
static __device__ __forceinline__ u16 f2bf(float f) {
    unsigned u = __builtin_bit_cast(unsigned, f);
    return (u16)((u + 0x7FFFu + ((u >> 16) & 1u)) >> 16);
}
// f32 -> fp8 e4m3 (OCP)
static __device__ __forceinline__ u8 f2fp8(float f) {
    __hip_fp8_e4m3 t(f);
    return (u8)t.__x;
}

// fill one conv channel's LDS row (linear-k layout, kk = tap*300+e)
template<int KT>
static __device__ __forceinline__ void fill_row(const float* __restrict__ src,
                                                u8* __restrict__ tilerow, int lane) {
    const float4* s4 = reinterpret_cast<const float4*>(src);
    for (int i4 = lane; i4 < 75 * KT; i4 += 64) {
        float4 v = s4[i4];
        float vv[4] = {v.x, v.y, v.z, v.w};
#pragma unroll
        for (int k = 0; k < 4; ++k) {
            int p = i4 * 4 + k;
            int e = p / KT, tap = p - e * KT;
            tilerow[tap * 300 + e] = f2fp8(vv[k] * 16.0f);
        }
    }
}

// ---------------------------------------------------------------------------
// prep v4 (1385 blocks x 256):
//  [0,640):     wpack3 fp8 x16 (conv B panel)
//  [640,896):   wpre2 bf16  [s][ks10][g512][q][j]
//  [896,1152):  whh_pk bf16 [s][ks4][g512][q][j]
//  [1152,1216): lxw_pk bf16 [s][ks8][c128][q][j]
//  [1216,1248): lyw_pk bf16 [s][ks4][c64][q][j]
//  [1248,1384): aw1T 32x32 f32 transposes
//  [1384]:      bcomb
// ---------------------------------------------------------------------------
__global__ __launch_bounds__(256) void prep(
        const float* __restrict__ w3, const float* __restrict__ b3,
        const float* __restrict__ w4, const float* __restrict__ b4,
        const float* __restrict__ w5, const float* __restrict__ b5,
        const float* __restrict__ w_ih, const float* __restrict__ w_hh,
        const float* __restrict__ lxw, const float* __restrict__ lyw,
        const float* __restrict__ aw1,
        u8* __restrict__ wpack3, u16* __restrict__ wpre2,
        u16* __restrict__ whh_pk, u16* __restrict__ lxw_pk, u16* __restrict__ lyw_pk,
        float* __restrict__ bcomb, float* __restrict__ aw1T) {
    const int blk = blockIdx.x, tid = threadIdx.x;

    if (blk < 640) {                     // ---- wpack3 ----
        __shared__ u8 tile4[4][1504];
        const int s = blk / 80, cq = blk % 80;
        const int c0 = cq * 4;
        const int ch4 = tid >> 6, lane = tid & 63;
        for (int i = tid; i < 1504; i += 256)
            reinterpret_cast<u32*>(&tile4[0][0])[i] = 0u;
        __syncthreads();
        const int c = c0 + ch4;
        if (cq < 25)      fill_row<3>(w3 + (size_t)((s * 100 + c      ) * 300) * 3, &tile4[ch4][0], lane);
        else if (cq < 50) fill_row<4>(w4 + (size_t)((s * 100 + c - 100) * 300) * 4, &tile4[ch4][0], lane);
        else if (cq < 75) fill_row<5>(w5 + (size_t)((s * 100 + c - 200) * 300) * 5, &tile4[ch4][0], lane);
        __syncthreads();
        u32* dst0 = reinterpret_cast<u32*>(wpack3) + (size_t)s * 120320;
        const int kss = tid >> 5, m = tid & 31;
        const int ch = m >> 3, b0 = (m & 7) * 4;
#pragma unroll
        for (int ksb = 0; ksb < 6; ++ksb) {
            int ks = ksb * 8 + kss;
            if (ks < 47) {
                int kk = ks * 32 + b0;
                u32 v = (u32)tile4[ch][kk] | ((u32)tile4[ch][kk + 1] << 8)
                      | ((u32)tile4[ch][kk + 2] << 16) | ((u32)tile4[ch][kk + 3] << 24);
                dst0[(size_t)ks * 2560 + cq * 32 + m] = v;
            }
        }
    } else if (blk < 1248) {             // ---- bf16 B-frag packs ----
        __shared__ u16 tile2[16][320];
        const int ch = tid >> 4, lane = tid & 15;
        const float* src; u32* dst0; int nks, slab;
        if (blk < 896) {                 // wpre2: G=512, K=320(300 pad)
            int u = blk - 640, s = u >> 5, gg = u & 31;
            int g = gg * 16 + ch;
            src = w_ih + (size_t)(s * 512 + g) * 300;
            const float4* s4 = reinterpret_cast<const float4*>(src);
            for (int i4 = lane; i4 < 75; i4 += 16) {
                float4 v = s4[i4];
                tile2[ch][i4*4+0]=f2bf(v.x); tile2[ch][i4*4+1]=f2bf(v.y);
                tile2[ch][i4*4+2]=f2bf(v.z); tile2[ch][i4*4+3]=f2bf(v.w);
            }
            for (int p = 300 + lane; p < 320; p += 16) tile2[ch][p] = 0;
            dst0 = reinterpret_cast<u32*>(wpre2 + (size_t)s * 163840) + gg * 256;
            nks = 10; slab = 8192;
        } else if (blk < 1152) {         // whh_pk: G=512, K=128
            int u = blk - 896, s = u >> 5, gg = u & 31;
            int g = gg * 16 + ch;
            const float4* s4 = reinterpret_cast<const float4*>(w_hh + (size_t)(s * 512 + g) * 128);
            for (int i4 = lane; i4 < 32; i4 += 16) {
                float4 v = s4[i4];
                tile2[ch][i4*4+0]=f2bf(v.x); tile2[ch][i4*4+1]=f2bf(v.y);
                tile2[ch][i4*4+2]=f2bf(v.z); tile2[ch][i4*4+3]=f2bf(v.w);
            }
            dst0 = reinterpret_cast<u32*>(whh_pk + (size_t)s * 65536) + gg * 256;
            nks = 4; slab = 8192;
        } else if (blk < 1216) {         // lxw_pk: G=128, K=256
            int u = blk - 1152, s = u >> 3, gg = u & 7;
            int g = gg * 16 + ch;
            const float4* s4 = reinterpret_cast<const float4*>(lxw + (size_t)(s * 128 + g) * 256);
            for (int i4 = lane; i4 < 64; i4 += 16) {
                float4 v = s4[i4];
                tile2[ch][i4*4+0]=f2bf(v.x); tile2[ch][i4*4+1]=f2bf(v.y);
                tile2[ch][i4*4+2]=f2bf(v.z); tile2[ch][i4*4+3]=f2bf(v.w);
            }
            dst0 = reinterpret_cast<u32*>(lxw_pk + (size_t)s * 32768) + gg * 256;
            nks = 8; slab = 2048;
        } else {                         // lyw_pk: G=64, K=128
            int u = blk - 1216, s = u >> 2, gg = u & 3;
            int g = gg * 16 + ch;
            const float4* s4 = reinterpret_cast<const float4*>(lyw + (size_t)(s * 64 + g) * 128);
            for (int i4 = lane; i4 < 32; i4 += 16) {
                float4 v = s4[i4];
                tile2[ch][i4*4+0]=f2bf(v.x); tile2[ch][i4*4+1]=f2bf(v.y);
                tile2[ch][i4*4+2]=f2bf(v.z); tile2[ch][i4*4+3]=f2bf(v.w);
            }
            dst0 = reinterpret_cast<u32*>(lyw_pk + (size_t)s * 8192) + gg * 256;
            nks = 4; slab = 1024;
        }
        __syncthreads();
        const int mch = tid >> 4, rem = (tid * 2) & 31;
        for (int ks = 0; ks < nks; ++ks) {
            u32 v = (u32)tile2[mch][ks * 32 + rem] | ((u32)tile2[mch][ks * 32 + rem + 1] << 16);
            dst0[(size_t)ks * slab + tid] = v;
        }
    } else if (blk < 1384) {             // ---- aw1T transpose ----
        __shared__ float ldsT[32][33];
        int u = blk - 1248;
        int it = u >> 3, jt = u & 7;
        int i0 = it * 32, t0 = jt * 32;
        int ivalid = (i0 + 32 <= 528) ? 32 : (528 - i0);
        const int row = tid >> 3, cf = tid & 7;
        float4 v = make_float4(0.f, 0.f, 0.f, 0.f);
        if (cf * 4 < ivalid)
            v = *reinterpret_cast<const float4*>(aw1 + (size_t)(t0 + row) * 528 + i0 + cf * 4);
        ldsT[cf * 4 + 0][row] = v.x; ldsT[cf * 4 + 1][row] = v.y;
        ldsT[cf * 4 + 2][row] = v.z; ldsT[cf * 4 + 3][row] = v.w;
        __syncthreads();
        if (row < ivalid) {
            float4 w;
            w.x = ldsT[row][cf * 4 + 0]; w.y = ldsT[row][cf * 4 + 1];
            w.z = ldsT[row][cf * 4 + 2]; w.w = ldsT[row][cf * 4 + 3];
            *reinterpret_cast<float4*>(aw1T + (size_t)(i0 + row) * 256 + t0 + cf * 4) = w;
        }
    } else {                             // ---- bcomb ----
        for (int i = tid; i < 2560; i += 256) {
            int c = i % 320, s = i / 320;
            float bv = 0.f;
            if (c < 100)      bv = b3[s*100 + c];
            else if (c < 200) bv = b4[s*100 + c - 100];
            else if (c < 300) bv = b5[s*100 + c - 200];
            bcomb[i] = bv;
        }
    }
}

// ---------------------------------------------------------------------------
// conv via fp8 MFMA (unchanged from R13/R14)
// ---------------------------------------------------------------------------
__global__ __launch_bounds__(512, 1) void conv_mfma(const float* __restrict__ news,
                                                    const u8* __restrict__ wpack3,
                                                    const float* __restrict__ bcomb,
                                                    u16* __restrict__ text_bf) {
    __shared__ u8 xs[5 * 10816];
    __shared__ float part[10][320];
    const int tid = threadIdx.x, bid = blockIdx.x;
    const int s = bid & 7, rr_ = bid >> 3, b = rr_ >> 1, half = rr_ & 1;
    const int l = tid & 63, wvi = tid >> 6;
    const int wm = wvi >> 2, wn = wvi & 3;
    const int q = l >> 4, r16 = l & 15;

    const u8* gp[5];
#pragma unroll
    for (int nt = 0; nt < 5; ++nt) {
        int c = wn * 80 + nt * 16 + r16;
        gp[nt] = wpack3 + (size_t)s * 481280 + c * 32 + q * 8;
    }

    u64 bf0[5], bf1[5];
#pragma unroll
    for (int nt = 0; nt < 5; ++nt) bf0[nt] = *reinterpret_cast<const u64*>(gp[nt]);
#pragma unroll
    for (int nt = 0; nt < 5; ++nt) bf1[nt] = *reinterpret_cast<const u64*>(gp[nt] + 10240);

    {
        const float4* xg = reinterpret_cast<const float4*>(
            news + (size_t)((b * 8 + s) * 10 + half * 5) * 9600);
        for (int base = 0; base < 12000; base += 4096) {
            float4 v[8];
#pragma unroll
            for (int j = 0; j < 8; ++j) {
                int idx = base + j * 512 + tid;
                if (idx < 12000) v[j] = xg[idx];
            }
#pragma unroll
            for (int j = 0; j < 8; ++j) {
                int idx = base + j * 512 + tid;
                if (idx < 12000) {
                    int day = idx / 2400, rem = idx - day * 2400;
                    u32 o = (u32)f2fp8(v[j].x) | ((u32)f2fp8(v[j].y) << 8)
                          | ((u32)f2fp8(v[j].z) << 16) | ((u32)f2fp8(v[j].w) << 24);
                    *reinterpret_cast<u32*>(&xs[day * 10816 + rem * 4]) = o;
                }
            }
        }
        for (int i = tid; i < 1520; i += 512) {
            int day = i / 304, p = i - day * 304;
            *reinterpret_cast<u32*>(&xs[day * 10816 + 9600 + p * 4]) = 0u;
        }
    }
    __syncthreads();

    f32x4 acc[5][5];
#pragma unroll
    for (int mt = 0; mt < 5; ++mt)
#pragma unroll
        for (int nt = 0; nt < 5; ++nt) acc[mt][nt] = (f32x4)(0.f);

#define LOADA(dst, ks) do {                                                       \
    _Pragma("unroll")                                                             \
    for (int mt_ = 0; mt_ < 5; ++mt_) {                                           \
        int di_ = wm * 5 + mt_;                                                   \
        int off_ = (di_ >> 1) * 10816 + (((di_ & 1) << 4) + r16) * 300            \
                   + (ks) * 32 + q * 8;                                           \
        u32 lo_ = *reinterpret_cast<const u32*>(&xs[off_]);                       \
        u32 hi_ = *reinterpret_cast<const u32*>(&xs[off_ + 4]);                   \
        dst[mt_] = (u64)lo_ | ((u64)hi_ << 32);                                   \
    } } while (0)

#define MFMAS(bfv, av) do {                                                       \
    _Pragma("unroll")                                                             \
    for (int nt_ = 0; nt_ < 5; ++nt_)                                             \
        _Pragma("unroll")                                                         \
        for (int mt_ = 0; mt_ < 5; ++mt_)                                         \
            acc[mt_][nt_] = __builtin_amdgcn_mfma_f32_16x16x32_fp8_fp8(          \
                (long long)av[mt_], (long long)bfv[nt_], acc[mt_][nt_], 0, 0, 0); \
    } while (0)

    for (int ks = 0; ks < 46; ks += 2) {
        u64 a0[5], a1[5];
        LOADA(a0, ks);
        MFMAS(bf0, a0);
#pragma unroll
        for (int nt = 0; nt < 5; ++nt)
            bf0[nt] = *reinterpret_cast<const u64*>(gp[nt] + (ks + 2) * 10240);

        LOADA(a1, ks + 1);
        MFMAS(bf1, a1);
        if (ks + 3 < 47) {
#pragma unroll
            for (int nt = 0; nt < 5; ++nt)
                bf1[nt] = *reinterpret_cast<const u64*>(gp[nt] + (ks + 3) * 10240);
        }
    }
    {
        u64 a0[5];
        LOADA(a0, 46);
        MFMAS(bf0, a0);
    }
#undef LOADA
#undef MFMAS

#pragma unroll
    for (int mt = 0; mt < 5; ++mt) {
        const int di = wm * 5 + mt;
        const int nwb = (di & 1) << 4;
#pragma unroll
        for (int nt = 0; nt < 5; ++nt) {
            int oc = wn * 80 + nt * 16 + r16;
            int L = (oc < 100) ? 30 : (oc < 200) ? 29 : 28;
            float mx = -3e38f;
#pragma unroll
            for (int rr = 0; rr < 4; ++rr) {
                int nw = nwb + q * 4 + rr;
                if (nw < L) mx = fmaxf(mx, acc[mt][nt][rr]);
            }
            mx = fmaxf(mx, __shfl_xor(mx, 16));
            mx = fmaxf(mx, __shfl_xor(mx, 32));
            if (l < 16) part[di][wn * 80 + nt * 16 + l] = mx;
        }
    }
    __syncthreads();
    for (int i = tid; i < 1600; i += 512) {
        int day = i / 320, oc = i - day * 320;
        float mx = fmaxf(part[2 * day][oc], part[2 * day + 1][oc]);
        text_bf[((size_t)(s * 16 + b) * 10 + half * 5 + day) * 320 + oc] =
            f2bf(mx * 0.0625f + bcomb[s * 320 + oc]);
    }
}

// ---------------------------------------------------------------------------
// stock_tail v2: one block per stock s (8 blocks x 512 thr, 8 waves).
// MFMA-batched LSTM over all 16 batch rows: per step,
//   gates[16][512] = bias + text_d[16x320]@w_ih^T + h[16x128]@w_hh^T
// (wave wv owns 64 gate cols = 4 n-tiles; pre recomputed per-d -> no pre buf).
// Activations: 4 (b,h) pairs/thread, c-state in regs, h -> swizzled bf16
// A-tile in LDS. linX/linY as 16-row MFMAs from packed B-frags.
// ---------------------------------------------------------------------------
__global__ __launch_bounds__(512, 1) void stock_tail(const u16* __restrict__ text_bf,
                                                     const u16* __restrict__ wpre2,
                                                     const u16* __restrict__ whh_pk,
                                                     const u16* __restrict__ lxw_pk,
                                                     const u16* __restrict__ lyw_pk,
                                                     const float* __restrict__ b_ih,
                                                     const float* __restrict__ b_hh,
                                                     const float* __restrict__ lxb,
                                                     const float* __restrict__ lyb,
                                                     float* __restrict__ total) {
    __shared__ float gates[16 * GP_];        // 32.9 KB
    __shared__ u16 hA[16 * 128];             // 4 KB, swizzled A-tile
    __shared__ u16 combA[16 * 256];          // 8 KB
    __shared__ u16 hxA[16 * 128];            // 4 KB
    const int s = blockIdx.x;
    const int t = threadIdx.x, l = t & 63, wv = t >> 6, q = l >> 4, r16 = l & 15;

    // B-frag pointers (wave wv owns g in [wv*64, wv*64+64))
    const u16 *gpre[4], *ghh[4];
    float bias[4];
#pragma unroll
    for (int nt = 0; nt < 4; ++nt) {
        int g = wv * 64 + nt * 16 + r16;
        gpre[nt] = wpre2  + (size_t)s * 163840 + g * 32 + q * 8;
        ghh[nt]  = whh_pk + (size_t)s * 65536  + g * 32 + q * 8;
        bias[nt] = b_ih[s * G4_ + g] + b_hh[s * G4_ + g];
    }
    // text A-frag base: row b=r16, k-chunk q
    const u16* atext = text_bf + ((size_t)(s * 16 + r16) * 10) * 320 + q * 8;

    // zero h0
    reinterpret_cast<u64*>(hA)[t & 255] = 0ull;   // 256 u64 = 4KB (written 2x, fine)
    float cst[4] = {0.f, 0.f, 0.f, 0.f};
    float hsum[4] = {0.f, 0.f, 0.f, 0.f};
    __syncthreads();

    for (int d = 0; d < D_; ++d) {
        f32x4 acc[4];
#pragma unroll
        for (int nt = 0; nt < 4; ++nt) acc[nt] = (f32x4)(bias[nt]);
        // pre part: text_d @ w_ih^T  (10 k-steps)
        const u16* ad = atext + d * 320;
        for (int ks = 0; ks < 10; ++ks) {
            short8 a = *reinterpret_cast<const short8*>(ad + ks * 32);
#pragma unroll
            for (int nt = 0; nt < 4; ++nt) {
                short8 bfr = *reinterpret_cast<const short8*>(gpre[nt] + ks * 16384);
                acc[nt] = __builtin_amdgcn_mfma_f32_16x16x32_bf16(a, bfr, acc[nt], 0, 0, 0);
            }
        }
        // h part: h @ w_hh^T  (4 k-steps), swizzled hA reads
#pragma unroll
        for (int ks2 = 0; ks2 < 4; ++ks2) {
            int gran = (ks2 * 4 + q) ^ (r16 & 7);
            short8 ah = *reinterpret_cast<const short8*>(&hA[r16 * 128 + gran * 8]);
#pragma unroll
            for (int nt = 0; nt < 4; ++nt) {
                short8 bfr = *reinterpret_cast<const short8*>(ghh[nt] + ks2 * 16384);
                acc[nt] = __builtin_amdgcn_mfma_f32_16x16x32_bf16(ah, bfr, acc[nt], 0, 0, 0);
            }
        }
        __syncthreads();   // prior gate reads + hA reads done
#pragma unroll
        for (int nt = 0; nt < 4; ++nt) {
            int g = wv * 64 + nt * 16 + r16;
#pragma unroll
            for (int rr = 0; rr < 4; ++rr)
                gates[(q * 4 + rr) * GP_ + g] = acc[nt][rr];
        }
        __syncthreads();   // gates visible
        // activations: 4 (b,h) pairs per thread
#pragma unroll
        for (int k = 0; k < 4; ++k) {
            int p = t + 512 * k;
            int b = p >> 7, h = p & 127;
            float ig = 1.f / (1.f + expf(-gates[b * GP_ + h]));
            float fg = 1.f / (1.f + expf(-gates[b * GP_ + 128 + h]));
            float gg = tanhf(gates[b * GP_ + 256 + h]);
            float og = 1.f / (1.f + expf(-gates[b * GP_ + 384 + h]));
            float c = fg * cst[k] + ig * gg;
            cst[k] = c;
            float hv = og * tanhf(c);
            hsum[k] += hv;
            int swzg = (h >> 3) ^ (b & 7);
            hA[b * 128 + swzg * 8 + (h & 7)] = f2bf(hv);
            if (d == D_ - 1) {
                int cg1 = (h >> 3) ^ (b & 7);                 // col h
                int cg2 = ((128 + h) >> 3) ^ (b & 7);         // col 128+h
                combA[b * 256 + cg1 * 8 + (h & 7)] = f2bf(hv);
                combA[b * 256 + cg2 * 8 + (h & 7)] = f2bf(hsum[k]);
            }
        }
        __syncthreads();   // hA/combA visible for next phase
    }

    // linX: hx[16][128] = relu(comb[16][256] @ lxw^T + lxb); wave wv -> cols wv*16+r16
    {
        int col = wv * 16 + r16;
        f32x4 xacc = (f32x4)(lxb[s * H_ + col]);
        for (int ks = 0; ks < 8; ++ks) {
            int gran = (ks * 4 + q) ^ (r16 & 7);
            short8 a = *reinterpret_cast<const short8*>(&combA[r16 * 256 + gran * 8]);
            short8 bfr = *reinterpret_cast<const short8*>(
                lxw_pk + (size_t)s * 32768 + ks * 4096 + col * 32 + q * 8);
            xacc = __builtin_amdgcn_mfma_f32_16x16x32_bf16(a, bfr, xacc, 0, 0, 0);
        }
#pragma unroll
        for (int rr = 0; rr < 4; ++rr) {
            int b = q * 4 + rr;
            float v = fmaxf(xacc[rr], 0.f);
            int swzg = (col >> 3) ^ (b & 7);
            hxA[b * 128 + swzg * 8 + (col & 7)] = f2bf(v);
        }
    }
    __syncthreads();

    // linY: out[16][64] = relu(hx[16][128] @ lyw^T + lyb); waves 0-3
    if (wv < 4) {
        int col = wv * 16 + r16;
        f32x4 yacc = (f32x4)(lyb[s * 64 + col]);
#pragma unroll
        for (int ks = 0; ks < 4; ++ks) {
            int gran = (ks * 4 + q) ^ (r16 & 7);
            short8 a = *reinterpret_cast<const short8*>(&hxA[r16 * 128 + gran * 8]);
            short8 bfr = *reinterpret_cast<const short8*>(
                lyw_pk + (size_t)s * 8192 + ks * 2048 + col * 32 + q * 8);
            yacc = __builtin_amdgcn_mfma_f32_16x16x32_bf16(a, bfr, yacc, 0, 0, 0);
        }
#pragma unroll
        for (int rr = 0; rr < 4; ++rr) {
            int b = q * 4 + rr;
            total[(size_t)b * 512 + s * 64 + col] = fmaxf(yacc[rr], 0.f);
        }
    }
}

// ---------------------------------------------------------------------------
// head_feats (unchanged)
// ---------------------------------------------------------------------------
__global__ __launch_bounds__(512) void head_feats(const float* __restrict__ total,
                                                  const float* __restrict__ sf,
                                                  const float* __restrict__ w1, const float* __restrict__ b1,
                                                  const float* __restrict__ w2, const float* __restrict__ b2,
                                                  const float* __restrict__ aw1T, const float* __restrict__ ab1,
                                                  const float* __restrict__ aw2, const float* __restrict__ ab2,
                                                  const float* __restrict__ avar,
                                                  float* __restrict__ out) {
    __shared__ __align__(16) float tr[TOT_];
    __shared__ float hid[MID_];
    __shared__ float h1f[24];
    __shared__ float pA[MID_], pB[MID_];
    const int bb = blockIdx.x, t = threadIdx.x;
    if (t < 128)
        reinterpret_cast<float4*>(tr)[t] = reinterpret_cast<const float4*>(total + (size_t)bb * 512)[t];
    if (t < 24) {
        float acc = b1[t];
        for (int i = 0; i < SDIM_; ++i) acc = fmaf(sf[bb * SDIM_ + i], w1[t * SDIM_ + i], acc);
        h1f[t] = fmaxf(acc, 0.f);
    }
    __syncthreads();
    if (t < 16) {
        float acc = b2[t];
        for (int i = 0; i < 24; ++i) acc = fmaf(h1f[i], w2[t * 24 + i], acc);
        tr[512 + t] = acc;
    }
    __syncthreads();
    {
        const int j = t & 255, hf = t >> 8;
        const int ilo = hf ? 264 : 0, ihi = hf ? 528 : 264;
        const float* wv = aw1T + j;
        float a0 = 0.f, a1 = 0.f, a2 = 0.f, a3 = 0.f;
        for (int i = ilo; i < ihi; i += 4) {
            a0 = fmaf(tr[i + 0], wv[(size_t)(i + 0) * 256], a0);
            a1 = fmaf(tr[i + 1], wv[(size_t)(i + 1) * 256], a1);
            a2 = fmaf(tr[i + 2], wv[(size_t)(i + 2) * 256], a2);
            a3 = fmaf(tr[i + 3], wv[(size_t)(i + 3) * 256], a3);
        }
        float p = (a0 + a1) + (a2 + a3);
        if (hf) pB[j] = p; else pA[j] = p;
    }
    __syncthreads();
    if (t < MID_) hid[t] = fmaxf(pA[t] + pB[t] + ab1[t], 0.f);
    __syncthreads();
    if (t < 8) {
        float acc = ab2[t];
        const float* wv = aw2 + (size_t)t * MID_;
        for (int i = 0; i < MID_; ++i) acc = fmaf(hid[i], wv[i], acc);
        out[bb * 8 + t] = tanhf(acc);
    }
    if (bb == 0 && t >= 8 && t < 16) out[128 + (t - 8)] = expf(avar[t - 8]);
}

// ---------------------------------------------------------------------------
extern "C" void kernel_launch(void* const* d_in, const int* in_sizes, int n_in,
                              void* d_out, int out_size, void* d_ws, size_t ws_size,
                              hipStream_t stream) {
    const float* news = (const float*)d_in[0];
    const float* sf   = (const float*)d_in[1];
    const float* w3   = (const float*)d_in[2];  const float* b3 = (const float*)d_in[3];
    const float* w4   = (const float*)d_in[4];  const float* b4 = (const float*)d_in[5];
    const float* w5   = (const float*)d_in[6];  const float* b5 = (const float*)d_in[7];
    const float* w_ih = (const float*)d_in[8];  const float* w_hh = (const float*)d_in[9];
    const float* b_ih = (const float*)d_in[10]; const float* b_hh = (const float*)d_in[11];
    const float* lxw  = (const float*)d_in[12]; const float* lxb = (const float*)d_in[13];
    const float* lyw  = (const float*)d_in[14]; const float* lyb = (const float*)d_in[15];
    const float* w1   = (const float*)d_in[16]; const float* b1 = (const float*)d_in[17];
    const float* w2   = (const float*)d_in[18]; const float* b2 = (const float*)d_in[19];
    const float* aw1  = (const float*)d_in[20]; const float* ab1 = (const float*)d_in[21];
    const float* aw2  = (const float*)d_in[22]; const float* ab2 = (const float*)d_in[23];
    const float* avar = (const float*)d_in[24];

    char* ws = (char*)d_ws;
    u8*    wpack3  = (u8*)ws;                                   // 3,850,240 B
    u16*   wpre2   = (u16*)(ws + 3850240);                      // 2,621,440 B
    u16*   whh_pk  = (u16*)(ws + 6471680);                      // 1,048,576 B
    u16*   lxw_pk  = (u16*)(ws + 7520256);                      //   524,288 B
    u16*   lyw_pk  = (u16*)(ws + 8044544);                      //   131,072 B
    float* bcomb   = (float*)(ws + 8175616);                    //    10,240 B
    u16*   text_bf = (u16*)(ws + 8185856);                      //   819,200 B
    float* total   = (float*)(ws + 9005056);                    //    32,768 B
    float* aw1T    = (float*)(ws + 9037824);                    //   540,672 B (end ~9.6 MB)

    prep<<<1385, 256, 0, stream>>>(w3, b3, w4, b4, w5, b5, w_ih, w_hh, lxw, lyw, aw1,
                                   wpack3, wpre2, whh_pk, lxw_pk, lyw_pk, bcomb, aw1T);
    conv_mfma<<<256, 512, 0, stream>>>(news, wpack3, bcomb, text_bf);
    stock_tail<<<S_, 512, 0, stream>>>(text_bf, wpre2, whh_pk, lxw_pk, lyw_pk,
                                       b_ih, b_hh, lxb, lyb, total);
    head_feats<<<B_, 512, 0, stream>>>(total, sf, w1, b1, w2, b2, aw1T, ab1, aw2, ab2, avar, (float*)d_out);
}

// Round 16
// 113.895 us; speedup vs baseline: 1.6253x; 1.6253x over previous
//
#include <hip/hip_runtime.h>
#include <hip/hip_fp8.h>
#include <math.h>

// Problem dims
#define S_   8
#define B_   16
#define D_   10
#define N_   32
#define E_   300
#define H_   128
#define G4_  512
#define SDIM_ 96
#define MID_ 256
#define TOT_ 528

#define GP_  514   // gates LDS row pad (f32)

typedef unsigned short u16;
typedef unsigned int u32;
typedef unsigned char u8;
typedef unsigned long long u64;
typedef __attribute__((ext_vector_type(8))) short short8;
typedef __attribute__((ext_vector_type(4))) float f32x4;

// round-to-nearest-even f32 -> bf16
static __device__ __forceinline__ u16 f2bf(float f) {
    unsigned u = __builtin_bit_cast(unsigned, f);
    return (u16)((u + 0x7FFFu + ((u >> 16) & 1u)) >> 16);
}
// f32 -> fp8 e4m3 (OCP)
static __device__ __forceinline__ u8 f2fp8(float f) {
    __hip_fp8_e4m3 t(f);
    return (u8)t.__x;
}

// fill one conv channel's LDS row (linear-k layout, kk = tap*300+e)
template<int KT>
static __device__ __forceinline__ void fill_row(const float* __restrict__ src,
                                                u8* __restrict__ tilerow, int lane) {
    const float4* s4 = reinterpret_cast<const float4*>(src);
    for (int i4 = lane; i4 < 75 * KT; i4 += 64) {
        float4 v = s4[i4];
        float vv[4] = {v.x, v.y, v.z, v.w};
#pragma unroll
        for (int k = 0; k < 4; ++k) {
            int p = i4 * 4 + k;
            int e = p / KT, tap = p - e * KT;
            tilerow[tap * 300 + e] = f2fp8(vv[k] * 16.0f);
        }
    }
}

// ---------------------------------------------------------------------------
// prep v4 (unchanged from R15): wpack3 fp8, wpre2/whh_pk/lxw_pk/lyw_pk bf16
// B-frag packs, aw1T transpose, bcomb. 1385 blocks x 256.
// ---------------------------------------------------------------------------
__global__ __launch_bounds__(256) void prep(
        const float* __restrict__ w3, const float* __restrict__ b3,
        const float* __restrict__ w4, const float* __restrict__ b4,
        const float* __restrict__ w5, const float* __restrict__ b5,
        const float* __restrict__ w_ih, const float* __restrict__ w_hh,
        const float* __restrict__ lxw, const float* __restrict__ lyw,
        const float* __restrict__ aw1,
        u8* __restrict__ wpack3, u16* __restrict__ wpre2,
        u16* __restrict__ whh_pk, u16* __restrict__ lxw_pk, u16* __restrict__ lyw_pk,
        float* __restrict__ bcomb, float* __restrict__ aw1T) {
    const int blk = blockIdx.x, tid = threadIdx.x;

    if (blk < 640) {                     // ---- wpack3 ----
        __shared__ u8 tile4[4][1504];
        const int s = blk / 80, cq = blk % 80;
        const int c0 = cq * 4;
        const int ch4 = tid >> 6, lane = tid & 63;
        for (int i = tid; i < 1504; i += 256)
            reinterpret_cast<u32*>(&tile4[0][0])[i] = 0u;
        __syncthreads();
        const int c = c0 + ch4;
        if (cq < 25)      fill_row<3>(w3 + (size_t)((s * 100 + c      ) * 300) * 3, &tile4[ch4][0], lane);
        else if (cq < 50) fill_row<4>(w4 + (size_t)((s * 100 + c - 100) * 300) * 4, &tile4[ch4][0], lane);
        else if (cq < 75) fill_row<5>(w5 + (size_t)((s * 100 + c - 200) * 300) * 5, &tile4[ch4][0], lane);
        __syncthreads();
        u32* dst0 = reinterpret_cast<u32*>(wpack3) + (size_t)s * 120320;
        const int kss = tid >> 5, m = tid & 31;
        const int ch = m >> 3, b0 = (m & 7) * 4;
#pragma unroll
        for (int ksb = 0; ksb < 6; ++ksb) {
            int ks = ksb * 8 + kss;
            if (ks < 47) {
                int kk = ks * 32 + b0;
                u32 v = (u32)tile4[ch][kk] | ((u32)tile4[ch][kk + 1] << 8)
                      | ((u32)tile4[ch][kk + 2] << 16) | ((u32)tile4[ch][kk + 3] << 24);
                dst0[(size_t)ks * 2560 + cq * 32 + m] = v;
            }
        }
    } else if (blk < 1248) {             // ---- bf16 B-frag packs ----
        __shared__ u16 tile2[16][320];
        const int ch = tid >> 4, lane = tid & 15;
        u32* dst0; int nks, slab;
        if (blk < 896) {                 // wpre2: G=512, K=320(300 pad)
            int u = blk - 640, s = u >> 5, gg = u & 31;
            int g = gg * 16 + ch;
            const float4* s4 = reinterpret_cast<const float4*>(w_ih + (size_t)(s * 512 + g) * 300);
            for (int i4 = lane; i4 < 75; i4 += 16) {
                float4 v = s4[i4];
                tile2[ch][i4*4+0]=f2bf(v.x); tile2[ch][i4*4+1]=f2bf(v.y);
                tile2[ch][i4*4+2]=f2bf(v.z); tile2[ch][i4*4+3]=f2bf(v.w);
            }
            for (int p = 300 + lane; p < 320; p += 16) tile2[ch][p] = 0;
            dst0 = reinterpret_cast<u32*>(wpre2 + (size_t)s * 163840) + gg * 256;
            nks = 10; slab = 8192;
        } else if (blk < 1152) {         // whh_pk: G=512, K=128
            int u = blk - 896, s = u >> 5, gg = u & 31;
            int g = gg * 16 + ch;
            const float4* s4 = reinterpret_cast<const float4*>(w_hh + (size_t)(s * 512 + g) * 128);
            for (int i4 = lane; i4 < 32; i4 += 16) {
                float4 v = s4[i4];
                tile2[ch][i4*4+0]=f2bf(v.x); tile2[ch][i4*4+1]=f2bf(v.y);
                tile2[ch][i4*4+2]=f2bf(v.z); tile2[ch][i4*4+3]=f2bf(v.w);
            }
            dst0 = reinterpret_cast<u32*>(whh_pk + (size_t)s * 65536) + gg * 256;
            nks = 4; slab = 8192;
        } else if (blk < 1216) {         // lxw_pk: G=128, K=256
            int u = blk - 1152, s = u >> 3, gg = u & 7;
            int g = gg * 16 + ch;
            const float4* s4 = reinterpret_cast<const float4*>(lxw + (size_t)(s * 128 + g) * 256);
            for (int i4 = lane; i4 < 64; i4 += 16) {
                float4 v = s4[i4];
                tile2[ch][i4*4+0]=f2bf(v.x); tile2[ch][i4*4+1]=f2bf(v.y);
                tile2[ch][i4*4+2]=f2bf(v.z); tile2[ch][i4*4+3]=f2bf(v.w);
            }
            dst0 = reinterpret_cast<u32*>(lxw_pk + (size_t)s * 32768) + gg * 256;
            nks = 8; slab = 2048;
        } else {                         // lyw_pk: G=64, K=128
            int u = blk - 1216, s = u >> 2, gg = u & 3;
            int g = gg * 16 + ch;
            const float4* s4 = reinterpret_cast<const float4*>(lyw + (size_t)(s * 64 + g) * 128);
            for (int i4 = lane; i4 < 32; i4 += 16) {
                float4 v = s4[i4];
                tile2[ch][i4*4+0]=f2bf(v.x); tile2[ch][i4*4+1]=f2bf(v.y);
                tile2[ch][i4*4+2]=f2bf(v.z); tile2[ch][i4*4+3]=f2bf(v.w);
            }
            dst0 = reinterpret_cast<u32*>(lyw_pk + (size_t)s * 8192) + gg * 256;
            nks = 4; slab = 1024;
        }
        __syncthreads();
        const int mch = tid >> 4, rem = (tid * 2) & 31;
        for (int ks = 0; ks < nks; ++ks) {
            u32 v = (u32)tile2[mch][ks * 32 + rem] | ((u32)tile2[mch][ks * 32 + rem + 1] << 16);
            dst0[(size_t)ks * slab + tid] = v;
        }
    } else if (blk < 1384) {             // ---- aw1T transpose ----
        __shared__ float ldsT[32][33];
        int u = blk - 1248;
        int it = u >> 3, jt = u & 7;
        int i0 = it * 32, t0 = jt * 32;
        int ivalid = (i0 + 32 <= 528) ? 32 : (528 - i0);
        const int row = tid >> 3, cf = tid & 7;
        float4 v = make_float4(0.f, 0.f, 0.f, 0.f);
        if (cf * 4 < ivalid)
            v = *reinterpret_cast<const float4*>(aw1 + (size_t)(t0 + row) * 528 + i0 + cf * 4);
        ldsT[cf * 4 + 0][row] = v.x; ldsT[cf * 4 + 1][row] = v.y;
        ldsT[cf * 4 + 2][row] = v.z; ldsT[cf * 4 + 3][row] = v.w;
        __syncthreads();
        if (row < ivalid) {
            float4 w;
            w.x = ldsT[row][cf * 4 + 0]; w.y = ldsT[row][cf * 4 + 1];
            w.z = ldsT[row][cf * 4 + 2]; w.w = ldsT[row][cf * 4 + 3];
            *reinterpret_cast<float4*>(aw1T + (size_t)(i0 + row) * 256 + t0 + cf * 4) = w;
        }
    } else {                             // ---- bcomb ----
        for (int i = tid; i < 2560; i += 256) {
            int c = i % 320, s = i / 320;
            float bv = 0.f;
            if (c < 100)      bv = b3[s*100 + c];
            else if (c < 200) bv = b4[s*100 + c - 100];
            else if (c < 300) bv = b5[s*100 + c - 200];
            bcomb[i] = bv;
        }
    }
}

// ---------------------------------------------------------------------------
// conv via fp8 MFMA (unchanged from R13/R14)
// ---------------------------------------------------------------------------
__global__ __launch_bounds__(512, 1) void conv_mfma(const float* __restrict__ news,
                                                    const u8* __restrict__ wpack3,
                                                    const float* __restrict__ bcomb,
                                                    u16* __restrict__ text_bf) {
    __shared__ u8 xs[5 * 10816];
    __shared__ float part[10][320];
    const int tid = threadIdx.x, bid = blockIdx.x;
    const int s = bid & 7, rr_ = bid >> 3, b = rr_ >> 1, half = rr_ & 1;
    const int l = tid & 63, wvi = tid >> 6;
    const int wm = wvi >> 2, wn = wvi & 3;
    const int q = l >> 4, r16 = l & 15;

    const u8* gp[5];
#pragma unroll
    for (int nt = 0; nt < 5; ++nt) {
        int c = wn * 80 + nt * 16 + r16;
        gp[nt] = wpack3 + (size_t)s * 481280 + c * 32 + q * 8;
    }

    u64 bf0[5], bf1[5];
#pragma unroll
    for (int nt = 0; nt < 5; ++nt) bf0[nt] = *reinterpret_cast<const u64*>(gp[nt]);
#pragma unroll
    for (int nt = 0; nt < 5; ++nt) bf1[nt] = *reinterpret_cast<const u64*>(gp[nt] + 10240);

    {
        const float4* xg = reinterpret_cast<const float4*>(
            news + (size_t)((b * 8 + s) * 10 + half * 5) * 9600);
        for (int base = 0; base < 12000; base += 4096) {
            float4 v[8];
#pragma unroll
            for (int j = 0; j < 8; ++j) {
                int idx = base + j * 512 + tid;
                if (idx < 12000) v[j] = xg[idx];
            }
#pragma unroll
            for (int j = 0; j < 8; ++j) {
                int idx = base + j * 512 + tid;
                if (idx < 12000) {
                    int day = idx / 2400, rem = idx - day * 2400;
                    u32 o = (u32)f2fp8(v[j].x) | ((u32)f2fp8(v[j].y) << 8)
                          | ((u32)f2fp8(v[j].z) << 16) | ((u32)f2fp8(v[j].w) << 24);
                    *reinterpret_cast<u32*>(&xs[day * 10816 + rem * 4]) = o;
                }
            }
        }
        for (int i = tid; i < 1520; i += 512) {
            int day = i / 304, p = i - day * 304;
            *reinterpret_cast<u32*>(&xs[day * 10816 + 9600 + p * 4]) = 0u;
        }
    }
    __syncthreads();

    f32x4 acc[5][5];
#pragma unroll
    for (int mt = 0; mt < 5; ++mt)
#pragma unroll
        for (int nt = 0; nt < 5; ++nt) acc[mt][nt] = (f32x4)(0.f);

#define LOADA(dst, ks) do {                                                       \
    _Pragma("unroll")                                                             \
    for (int mt_ = 0; mt_ < 5; ++mt_) {                                           \
        int di_ = wm * 5 + mt_;                                                   \
        int off_ = (di_ >> 1) * 10816 + (((di_ & 1) << 4) + r16) * 300            \
                   + (ks) * 32 + q * 8;                                           \
        u32 lo_ = *reinterpret_cast<const u32*>(&xs[off_]);                       \
        u32 hi_ = *reinterpret_cast<const u32*>(&xs[off_ + 4]);                   \
        dst[mt_] = (u64)lo_ | ((u64)hi_ << 32);                                   \
    } } while (0)

#define MFMAS(bfv, av) do {                                                       \
    _Pragma("unroll")                                                             \
    for (int nt_ = 0; nt_ < 5; ++nt_)                                             \
        _Pragma("unroll")                                                         \
        for (int mt_ = 0; mt_ < 5; ++mt_)                                         \
            acc[mt_][nt_] = __builtin_amdgcn_mfma_f32_16x16x32_fp8_fp8(          \
                (long long)av[mt_], (long long)bfv[nt_], acc[mt_][nt_], 0, 0, 0); \
    } while (0)

    for (int ks = 0; ks < 46; ks += 2) {
        u64 a0[5], a1[5];
        LOADA(a0, ks);
        MFMAS(bf0, a0);
#pragma unroll
        for (int nt = 0; nt < 5; ++nt)
            bf0[nt] = *reinterpret_cast<const u64*>(gp[nt] + (ks + 2) * 10240);

        LOADA(a1, ks + 1);
        MFMAS(bf1, a1);
        if (ks + 3 < 47) {
#pragma unroll
            for (int nt = 0; nt < 5; ++nt)
                bf1[nt] = *reinterpret_cast<const u64*>(gp[nt] + (ks + 3) * 10240);
        }
    }
    {
        u64 a0[5];
        LOADA(a0, 46);
        MFMAS(bf0, a0);
    }
#undef LOADA
#undef MFMAS

#pragma unroll
    for (int mt = 0; mt < 5; ++mt) {
        const int di = wm * 5 + mt;
        const int nwb = (di & 1) << 4;
#pragma unroll
        for (int nt = 0; nt < 5; ++nt) {
            int oc = wn * 80 + nt * 16 + r16;
            int L = (oc < 100) ? 30 : (oc < 200) ? 29 : 28;
            float mx = -3e38f;
#pragma unroll
            for (int rr = 0; rr < 4; ++rr) {
                int nw = nwb + q * 4 + rr;
                if (nw < L) mx = fmaxf(mx, acc[mt][nt][rr]);
            }
            mx = fmaxf(mx, __shfl_xor(mx, 16));
            mx = fmaxf(mx, __shfl_xor(mx, 32));
            if (l < 16) part[di][wn * 80 + nt * 16 + l] = mx;
        }
    }
    __syncthreads();
    for (int i = tid; i < 1600; i += 512) {
        int day = i / 320, oc = i - day * 320;
        float mx = fmaxf(part[2 * day][oc], part[2 * day + 1][oc]);
        text_bf[((size_t)(s * 16 + b) * 10 + half * 5 + day) * 320 + oc] =
            f2bf(mx * 0.0625f + bcomb[s * 320 + oc]);
    }
}

// ---------------------------------------------------------------------------
// lstm_pre via MFMA (resurrected R10 version): per (s,d) block computes
// pre[16b][512g] = text[16][320] x wpre[320][512] + biases. 80 blocks x 256.
// ---------------------------------------------------------------------------
__global__ __launch_bounds__(256) void lstm_pre_mfma(const u16* __restrict__ text_bf,
                                                     const u16* __restrict__ wpre2,
                                                     const float* __restrict__ b_ih,
                                                     const float* __restrict__ b_hh,
                                                     float* __restrict__ pre) {
    __shared__ u16 as16[16 * 320];
    const int sd = blockIdx.x, s = sd / 10, d = sd % 10;
    const int tid = threadIdx.x, l = tid & 63, w = tid >> 6, q = l >> 4, r16 = l & 15;

    for (int i = tid; i < 640; i += 256) {
        int r = i / 40, c = i % 40;
        *reinterpret_cast<float4*>(as16 + r * 320 + ((c ^ (r & 7)) << 3)) =
            *reinterpret_cast<const float4*>(text_bf + ((size_t)(s * 16 + r) * 10 + d) * 320 + c * 8);
    }
    __syncthreads();

    const u16* gpb[8];
#pragma unroll
    for (int nt = 0; nt < 8; ++nt) {
        int g = w * 128 + nt * 16 + r16;
        gpb[nt] = wpre2 + (size_t)s * 163840 + g * 32 + q * 8;
    }

    f32x4 acc[8];
#pragma unroll
    for (int nt = 0; nt < 8; ++nt) acc[nt] = (f32x4)(0.f);

    for (int ks = 0; ks < 10; ++ks) {
        short8 a = *reinterpret_cast<const short8*>(
            as16 + r16 * 320 + (((ks * 4 + q) ^ (r16 & 7)) << 3));
#pragma unroll
        for (int nt = 0; nt < 8; ++nt) {
            short8 bf = *reinterpret_cast<const short8*>(gpb[nt] + ks * 16384);
            acc[nt] = __builtin_amdgcn_mfma_f32_16x16x32_bf16(a, bf, acc[nt], 0, 0, 0);
        }
    }

#pragma unroll
    for (int nt = 0; nt < 8; ++nt) {
        int g = w * 128 + nt * 16 + r16;
        float bias = b_ih[s * G4_ + g] + b_hh[s * G4_ + g];
#pragma unroll
        for (int r = 0; r < 4; ++r) {
            int brow = q * 4 + r;
            pre[((size_t)sd * 16 + brow) * 512 + g] = acc[nt][r] + bias;
        }
    }
}

// ---------------------------------------------------------------------------
// stock_tail v3: one block per stock s (8 x 512 thr). ONLY the recurrence:
// gates = pre[d] (global, coalesced, prefetched) + h @ w_hh^T (MFMA, w_hh
// B-frags hoisted in 64 VGPRs -- NO global weight loads in the d-loop).
// Activations 4 pairs/thread, h -> swizzled bf16 A-tile; linX/linY MFMAs.
// ---------------------------------------------------------------------------
__global__ __launch_bounds__(512, 1) void stock_tail(const float* __restrict__ pre,
                                                     const u16* __restrict__ whh_pk,
                                                     const u16* __restrict__ lxw_pk,
                                                     const u16* __restrict__ lyw_pk,
                                                     const float* __restrict__ lxb,
                                                     const float* __restrict__ lyb,
                                                     float* __restrict__ total) {
    __shared__ float gates[16 * GP_];        // 32.9 KB
    __shared__ u16 hA[16 * 128];             // 4 KB swizzled A-tile
    __shared__ u16 combA[16 * 256];          // 8 KB
    __shared__ u16 hxA[16 * 128];            // 4 KB
    const int s = blockIdx.x;
    const int t = threadIdx.x, l = t & 63, wv = t >> 6, q = l >> 4, r16 = l & 15;

    // hoist w_hh B-frags (invariant across steps): 16 short8 = 64 VGPR
    short8 ghr[4][4];
#pragma unroll
    for (int ks2 = 0; ks2 < 4; ++ks2)
#pragma unroll
        for (int nt = 0; nt < 4; ++nt) {
            int g = wv * 64 + nt * 16 + r16;
            ghr[ks2][nt] = *reinterpret_cast<const short8*>(
                whh_pk + (size_t)s * 65536 + ks2 * 16384 + g * 32 + q * 8);
        }

    reinterpret_cast<u64*>(hA)[t] = 0ull;    // full 4 KB zero (512 u64)
    float cst[4] = {0.f, 0.f, 0.f, 0.f};
    float hsum[4] = {0.f, 0.f, 0.f, 0.f};

    float pc[16], pn[16];
#pragma unroll
    for (int k = 0; k < 4; ++k) {            // pre for d=0
        int p = t + 512 * k; int b = p >> 7, h = p & 127;
        const float* base = pre + ((size_t)((s * 10 + 0) * 16 + b)) * 512 + h;
#pragma unroll
        for (int g = 0; g < 4; ++g) pc[k * 4 + g] = base[g * 128];
    }
    __syncthreads();

    for (int d = 0; d < D_; ++d) {
        f32x4 acc[4];
#pragma unroll
        for (int nt = 0; nt < 4; ++nt) acc[nt] = (f32x4)(0.f);
#pragma unroll
        for (int ks2 = 0; ks2 < 4; ++ks2) {
            int gran = (ks2 * 4 + q) ^ (r16 & 7);
            short8 ah = *reinterpret_cast<const short8*>(&hA[r16 * 128 + gran * 8]);
#pragma unroll
            for (int nt = 0; nt < 4; ++nt)
                acc[nt] = __builtin_amdgcn_mfma_f32_16x16x32_bf16(ah, ghr[ks2][nt], acc[nt], 0, 0, 0);
        }
        if (d + 1 < D_) {                    // prefetch next pre (hides under barriers)
#pragma unroll
            for (int k = 0; k < 4; ++k) {
                int p = t + 512 * k; int b = p >> 7, h = p & 127;
                const float* base = pre + ((size_t)((s * 10 + d + 1) * 16 + b)) * 512 + h;
#pragma unroll
                for (int g = 0; g < 4; ++g) pn[k * 4 + g] = base[g * 128];
            }
        }
        __syncthreads();                     // prev activation's gates reads done
#pragma unroll
        for (int nt = 0; nt < 4; ++nt) {
            int g = wv * 64 + nt * 16 + r16;
#pragma unroll
            for (int rr = 0; rr < 4; ++rr)
                gates[(q * 4 + rr) * GP_ + g] = acc[nt][rr];
        }
        __syncthreads();                     // gates visible
#pragma unroll
        for (int k = 0; k < 4; ++k) {
            int p = t + 512 * k;
            int b = p >> 7, h = p & 127;
            float ig = 1.f / (1.f + expf(-(pc[k*4+0] + gates[b * GP_ + h])));
            float fg = 1.f / (1.f + expf(-(pc[k*4+1] + gates[b * GP_ + 128 + h])));
            float gg = tanhf(pc[k*4+2] + gates[b * GP_ + 256 + h]);
            float og = 1.f / (1.f + expf(-(pc[k*4+3] + gates[b * GP_ + 384 + h])));
            float c = fg * cst[k] + ig * gg;
            cst[k] = c;
            float hv = og * tanhf(c);
            hsum[k] += hv;
            hA[b * 128 + (((h >> 3) ^ (b & 7)) << 3) + (h & 7)] = f2bf(hv);
            if (d == D_ - 1) {
                combA[b * 256 + (((h >> 3) ^ (b & 7)) << 3) + (h & 7)] = f2bf(hv);
                combA[b * 256 + ((((128 + h) >> 3) ^ (b & 7)) << 3) + (h & 7)] = f2bf(hsum[k]);
            }
        }
#pragma unroll
        for (int i = 0; i < 16; ++i) pc[i] = pn[i];
        __syncthreads();                     // hA/combA visible
    }

    // linX: hx[16][128] = relu(comb[16][256] @ lxw^T + lxb)
    {
        int col = wv * 16 + r16;
        f32x4 xacc = (f32x4)(lxb[s * H_ + col]);
#pragma unroll
        for (int ks = 0; ks < 8; ++ks) {
            int gran = (ks * 4 + q) ^ (r16 & 7);
            short8 a = *reinterpret_cast<const short8*>(&combA[r16 * 256 + gran * 8]);
            short8 bfr = *reinterpret_cast<const short8*>(
                lxw_pk + (size_t)s * 32768 + ks * 4096 + col * 32 + q * 8);
            xacc = __builtin_amdgcn_mfma_f32_16x16x32_bf16(a, bfr, xacc, 0, 0, 0);
        }
#pragma unroll
        for (int rr = 0; rr < 4; ++rr) {
            int b = q * 4 + rr;
            float v = fmaxf(xacc[rr], 0.f);
            hxA[b * 128 + (((col >> 3) ^ (b & 7)) << 3) + (col & 7)] = f2bf(v);
        }
    }
    __syncthreads();

    // linY: out[16][64] = relu(hx[16][128] @ lyw^T + lyb); waves 0-3
    if (wv < 4) {
        int col = wv * 16 + r16;
        f32x4 yacc = (f32x4)(lyb[s * 64 + col]);
#pragma unroll
        for (int ks = 0; ks < 4; ++ks) {
            int gran = (ks * 4 + q) ^ (r16 & 7);
            short8 a = *reinterpret_cast<const short8*>(&hxA[r16 * 128 + gran * 8]);
            short8 bfr = *reinterpret_cast<const short8*>(
                lyw_pk + (size_t)s * 8192 + ks * 2048 + col * 32 + q * 8);
            yacc = __builtin_amdgcn_mfma_f32_16x16x32_bf16(a, bfr, yacc, 0, 0, 0);
        }
#pragma unroll
        for (int rr = 0; rr < 4; ++rr) {
            int b = q * 4 + rr;
            total[(size_t)b * 512 + s * 64 + col] = fmaxf(yacc[rr], 0.f);
        }
    }
}

// ---------------------------------------------------------------------------
// head_feats (unchanged)
// ---------------------------------------------------------------------------
__global__ __launch_bounds__(512) void head_feats(const float* __restrict__ total,
                                                  const float* __restrict__ sf,
                                                  const float* __restrict__ w1, const float* __restrict__ b1,
                                                  const float* __restrict__ w2, const float* __restrict__ b2,
                                                  const float* __restrict__ aw1T, const float* __restrict__ ab1,
                                                  const float* __restrict__ aw2, const float* __restrict__ ab2,
                                                  const float* __restrict__ avar,
                                                  float* __restrict__ out) {
    __shared__ __align__(16) float tr[TOT_];
    __shared__ float hid[MID_];
    __shared__ float h1f[24];
    __shared__ float pA[MID_], pB[MID_];
    const int bb = blockIdx.x, t = threadIdx.x;
    if (t < 128)
        reinterpret_cast<float4*>(tr)[t] = reinterpret_cast<const float4*>(total + (size_t)bb * 512)[t];
    if (t < 24) {
        float acc = b1[t];
        for (int i = 0; i < SDIM_; ++i) acc = fmaf(sf[bb * SDIM_ + i], w1[t * SDIM_ + i], acc);
        h1f[t] = fmaxf(acc, 0.f);
    }
    __syncthreads();
    if (t < 16) {
        float acc = b2[t];
        for (int i = 0; i < 24; ++i) acc = fmaf(h1f[i], w2[t * 24 + i], acc);
        tr[512 + t] = acc;
    }
    __syncthreads();
    {
        const int j = t & 255, hf = t >> 8;
        const int ilo = hf ? 264 : 0, ihi = hf ? 528 : 264;
        const float* wv = aw1T + j;
        float a0 = 0.f, a1 = 0.f, a2 = 0.f, a3 = 0.f;
        for (int i = ilo; i < ihi; i += 4) {
            a0 = fmaf(tr[i + 0], wv[(size_t)(i + 0) * 256], a0);
            a1 = fmaf(tr[i + 1], wv[(size_t)(i + 1) * 256], a1);
            a2 = fmaf(tr[i + 2], wv[(size_t)(i + 2) * 256], a2);
            a3 = fmaf(tr[i + 3], wv[(size_t)(i + 3) * 256], a3);
        }
        float p = (a0 + a1) + (a2 + a3);
        if (hf) pB[j] = p; else pA[j] = p;
    }
    __syncthreads();
    if (t < MID_) hid[t] = fmaxf(pA[t] + pB[t] + ab1[t], 0.f);
    __syncthreads();
    if (t < 8) {
        float acc = ab2[t];
        const float* wv = aw2 + (size_t)t * MID_;
        for (int i = 0; i < MID_; ++i) acc = fmaf(hid[i], wv[i], acc);
        out[bb * 8 + t] = tanhf(acc);
    }
    if (bb == 0 && t >= 8 && t < 16) out[128 + (t - 8)] = expf(avar[t - 8]);
}

// ---------------------------------------------------------------------------
extern "C" void kernel_launch(void* const* d_in, const int* in_sizes, int n_in,
                              void* d_out, int out_size, void* d_ws, size_t ws_size,
                              hipStream_t stream) {
    const float* news = (const float*)d_in[0];
    const float* sf   = (const float*)d_in[1];
    const float* w3   = (const float*)d_in[2];  const float* b3 = (const float*)d_in[3];
    const float* w4   = (const float*)d_in[4];  const float* b4 = (const float*)d_in[5];
    const float* w5   = (const float*)d_in[6];  const float* b5 = (const float*)d_in[7];
    const float* w_ih = (const float*)d_in[8];  const float* w_hh = (const float*)d_in[9];
    const float* b_ih = (const float*)d_in[10]; const float* b_hh = (const float*)d_in[11];
    const float* lxw  = (const float*)d_in[12]; const float* lxb = (const float*)d_in[13];
    const float* lyw  = (const float*)d_in[14]; const float* lyb = (const float*)d_in[15];
    const float* w1   = (const float*)d_in[16]; const float* b1 = (const float*)d_in[17];
    const float* w2   = (const float*)d_in[18]; const float* b2 = (const float*)d_in[19];
    const float* aw1  = (const float*)d_in[20]; const float* ab1 = (const float*)d_in[21];
    const float* aw2  = (const float*)d_in[22]; const float* ab2 = (const float*)d_in[23];
    const float* avar = (const float*)d_in[24];

    char* ws = (char*)d_ws;
    u8*    wpack3  = (u8*)ws;                                   // 3,850,240 B
    u16*   wpre2   = (u16*)(ws + 3850240);                      // 2,621,440 B
    u16*   whh_pk  = (u16*)(ws + 6471680);                      // 1,048,576 B
    u16*   lxw_pk  = (u16*)(ws + 7520256);                      //   524,288 B
    u16*   lyw_pk  = (u16*)(ws + 8044544);                      //   131,072 B
    float* bcomb   = (float*)(ws + 8175616);                    //    10,240 B
    u16*   text_bf = (u16*)(ws + 8185856);                      //   819,200 B
    float* total   = (float*)(ws + 9005056);                    //    32,768 B
    float* aw1T    = (float*)(ws + 9037824);                    //   540,672 B
    float* pre     = (float*)(ws + 9578496);                    // 2,621,440 B (end ~12.2 MB)

    prep<<<1385, 256, 0, stream>>>(w3, b3, w4, b4, w5, b5, w_ih, w_hh, lxw, lyw, aw1,
                                   wpack3, wpre2, whh_pk, lxw_pk, lyw_pk, bcomb, aw1T);
    conv_mfma<<<256, 512, 0, stream>>>(news, wpack3, bcomb, text_bf);
    lstm_pre_mfma<<<S_ * D_, 256, 0, stream>>>(text_bf, wpre2, b_ih, b_hh, pre);
    stock_tail<<<S_, 512, 0, stream>>>(pre, whh_pk, lxw_pk, lyw_pk, lxb, lyb, total);
    head_feats<<<B_, 512, 0, stream>>>(total, sf, w1, b1, w2, b2, aw1T, ab1, aw2, ab2, avar, (float*)d_out);
}

// Round 17
// 110.565 us; speedup vs baseline: 1.6743x; 1.0301x over previous
//
#include <hip/hip_runtime.h>
#include <hip/hip_fp8.h>
#include <math.h>

// Problem dims
#define S_   8
#define B_   16
#define D_   10
#define N_   32
#define E_   300
#define H_   128
#define G4_  512
#define SDIM_ 96
#define MID_ 256
#define TOT_ 528

#define GP_  514   // gates LDS row pad (f32)

typedef unsigned short u16;
typedef unsigned int u32;
typedef unsigned char u8;
typedef unsigned long long u64;
typedef __attribute__((ext_vector_type(8))) short short8;
typedef __attribute__((ext_vector_type(4))) float f32x4;

// round-to-nearest-even f32 -> bf16
static __device__ __forceinline__ u16 f2bf(float f) {
    unsigned u = __builtin_bit_cast(unsigned, f);
    return (u16)((u + 0x7FFFu + ((u >> 16) & 1u)) >> 16);
}
// f32 -> fp8 e4m3 (OCP)
static __device__ __forceinline__ u8 f2fp8(float f) {
    __hip_fp8_e4m3 t(f);
    return (u8)t.__x;
}

// fill one conv channel's LDS row (linear-k layout, kk = tap*300+e)
template<int KT>
static __device__ __forceinline__ void fill_row(const float* __restrict__ src,
                                                u8* __restrict__ tilerow, int lane) {
    const float4* s4 = reinterpret_cast<const float4*>(src);
    for (int i4 = lane; i4 < 75 * KT; i4 += 64) {
        float4 v = s4[i4];
        float vv[4] = {v.x, v.y, v.z, v.w};
#pragma unroll
        for (int k = 0; k < 4; ++k) {
            int p = i4 * 4 + k;
            int e = p / KT, tap = p - e * KT;
            tilerow[tap * 300 + e] = f2fp8(vv[k] * 16.0f);
        }
    }
}

// ---------------------------------------------------------------------------
// prep v4 (unchanged from R16)
// ---------------------------------------------------------------------------
__global__ __launch_bounds__(256) void prep(
        const float* __restrict__ w3, const float* __restrict__ b3,
        const float* __restrict__ w4, const float* __restrict__ b4,
        const float* __restrict__ w5, const float* __restrict__ b5,
        const float* __restrict__ w_ih, const float* __restrict__ w_hh,
        const float* __restrict__ lxw, const float* __restrict__ lyw,
        const float* __restrict__ aw1,
        u8* __restrict__ wpack3, u16* __restrict__ wpre2,
        u16* __restrict__ whh_pk, u16* __restrict__ lxw_pk, u16* __restrict__ lyw_pk,
        float* __restrict__ bcomb, float* __restrict__ aw1T) {
    const int blk = blockIdx.x, tid = threadIdx.x;

    if (blk < 640) {                     // ---- wpack3 ----
        __shared__ u8 tile4[4][1504];
        const int s = blk / 80, cq = blk % 80;
        const int c0 = cq * 4;
        const int ch4 = tid >> 6, lane = tid & 63;
        for (int i = tid; i < 1504; i += 256)
            reinterpret_cast<u32*>(&tile4[0][0])[i] = 0u;
        __syncthreads();
        const int c = c0 + ch4;
        if (cq < 25)      fill_row<3>(w3 + (size_t)((s * 100 + c      ) * 300) * 3, &tile4[ch4][0], lane);
        else if (cq < 50) fill_row<4>(w4 + (size_t)((s * 100 + c - 100) * 300) * 4, &tile4[ch4][0], lane);
        else if (cq < 75) fill_row<5>(w5 + (size_t)((s * 100 + c - 200) * 300) * 5, &tile4[ch4][0], lane);
        __syncthreads();
        u32* dst0 = reinterpret_cast<u32*>(wpack3) + (size_t)s * 120320;
        const int kss = tid >> 5, m = tid & 31;
        const int ch = m >> 3, b0 = (m & 7) * 4;
#pragma unroll
        for (int ksb = 0; ksb < 6; ++ksb) {
            int ks = ksb * 8 + kss;
            if (ks < 47) {
                int kk = ks * 32 + b0;
                u32 v = (u32)tile4[ch][kk] | ((u32)tile4[ch][kk + 1] << 8)
                      | ((u32)tile4[ch][kk + 2] << 16) | ((u32)tile4[ch][kk + 3] << 24);
                dst0[(size_t)ks * 2560 + cq * 32 + m] = v;
            }
        }
    } else if (blk < 1248) {             // ---- bf16 B-frag packs ----
        __shared__ u16 tile2[16][320];
        const int ch = tid >> 4, lane = tid & 15;
        u32* dst0; int nks, slab;
        if (blk < 896) {                 // wpre2: G=512, K=320(300 pad)
            int u = blk - 640, s = u >> 5, gg = u & 31;
            int g = gg * 16 + ch;
            const float4* s4 = reinterpret_cast<const float4*>(w_ih + (size_t)(s * 512 + g) * 300);
            for (int i4 = lane; i4 < 75; i4 += 16) {
                float4 v = s4[i4];
                tile2[ch][i4*4+0]=f2bf(v.x); tile2[ch][i4*4+1]=f2bf(v.y);
                tile2[ch][i4*4+2]=f2bf(v.z); tile2[ch][i4*4+3]=f2bf(v.w);
            }
            for (int p = 300 + lane; p < 320; p += 16) tile2[ch][p] = 0;
            dst0 = reinterpret_cast<u32*>(wpre2 + (size_t)s * 163840) + gg * 256;
            nks = 10; slab = 8192;
        } else if (blk < 1152) {         // whh_pk: G=512, K=128
            int u = blk - 896, s = u >> 5, gg = u & 31;
            int g = gg * 16 + ch;
            const float4* s4 = reinterpret_cast<const float4*>(w_hh + (size_t)(s * 512 + g) * 128);
            for (int i4 = lane; i4 < 32; i4 += 16) {
                float4 v = s4[i4];
                tile2[ch][i4*4+0]=f2bf(v.x); tile2[ch][i4*4+1]=f2bf(v.y);
                tile2[ch][i4*4+2]=f2bf(v.z); tile2[ch][i4*4+3]=f2bf(v.w);
            }
            dst0 = reinterpret_cast<u32*>(whh_pk + (size_t)s * 65536) + gg * 256;
            nks = 4; slab = 8192;
        } else if (blk < 1216) {         // lxw_pk: G=128, K=256
            int u = blk - 1152, s = u >> 3, gg = u & 7;
            int g = gg * 16 + ch;
            const float4* s4 = reinterpret_cast<const float4*>(lxw + (size_t)(s * 128 + g) * 256);
            for (int i4 = lane; i4 < 64; i4 += 16) {
                float4 v = s4[i4];
                tile2[ch][i4*4+0]=f2bf(v.x); tile2[ch][i4*4+1]=f2bf(v.y);
                tile2[ch][i4*4+2]=f2bf(v.z); tile2[ch][i4*4+3]=f2bf(v.w);
            }
            dst0 = reinterpret_cast<u32*>(lxw_pk + (size_t)s * 32768) + gg * 256;
            nks = 8; slab = 2048;
        } else {                         // lyw_pk: G=64, K=128
            int u = blk - 1216, s = u >> 2, gg = u & 3;
            int g = gg * 16 + ch;
            const float4* s4 = reinterpret_cast<const float4*>(lyw + (size_t)(s * 64 + g) * 128);
            for (int i4 = lane; i4 < 32; i4 += 16) {
                float4 v = s4[i4];
                tile2[ch][i4*4+0]=f2bf(v.x); tile2[ch][i4*4+1]=f2bf(v.y);
                tile2[ch][i4*4+2]=f2bf(v.z); tile2[ch][i4*4+3]=f2bf(v.w);
            }
            dst0 = reinterpret_cast<u32*>(lyw_pk + (size_t)s * 8192) + gg * 256;
            nks = 4; slab = 1024;
        }
        __syncthreads();
        const int mch = tid >> 4, rem = (tid * 2) & 31;
        for (int ks = 0; ks < nks; ++ks) {
            u32 v = (u32)tile2[mch][ks * 32 + rem] | ((u32)tile2[mch][ks * 32 + rem + 1] << 16);
            dst0[(size_t)ks * slab + tid] = v;
        }
    } else if (blk < 1384) {             // ---- aw1T transpose ----
        __shared__ float ldsT[32][33];
        int u = blk - 1248;
        int it = u >> 3, jt = u & 7;
        int i0 = it * 32, t0 = jt * 32;
        int ivalid = (i0 + 32 <= 528) ? 32 : (528 - i0);
        const int row = tid >> 3, cf = tid & 7;
        float4 v = make_float4(0.f, 0.f, 0.f, 0.f);
        if (cf * 4 < ivalid)
            v = *reinterpret_cast<const float4*>(aw1 + (size_t)(t0 + row) * 528 + i0 + cf * 4);
        ldsT[cf * 4 + 0][row] = v.x; ldsT[cf * 4 + 1][row] = v.y;
        ldsT[cf * 4 + 2][row] = v.z; ldsT[cf * 4 + 3][row] = v.w;
        __syncthreads();
        if (row < ivalid) {
            float4 w;
            w.x = ldsT[row][cf * 4 + 0]; w.y = ldsT[row][cf * 4 + 1];
            w.z = ldsT[row][cf * 4 + 2]; w.w = ldsT[row][cf * 4 + 3];
            *reinterpret_cast<float4*>(aw1T + (size_t)(i0 + row) * 256 + t0 + cf * 4) = w;
        }
    } else {                             // ---- bcomb ----
        for (int i = tid; i < 2560; i += 256) {
            int c = i % 320, s = i / 320;
            float bv = 0.f;
            if (c < 100)      bv = b3[s*100 + c];
            else if (c < 200) bv = b4[s*100 + c - 100];
            else if (c < 300) bv = b5[s*100 + c - 200];
            bcomb[i] = bv;
        }
    }
}

// ---------------------------------------------------------------------------
// conv via fp8 MFMA (unchanged from R13/R14/R16)
// ---------------------------------------------------------------------------
__global__ __launch_bounds__(512, 1) void conv_mfma(const float* __restrict__ news,
                                                    const u8* __restrict__ wpack3,
                                                    const float* __restrict__ bcomb,
                                                    u16* __restrict__ text_bf) {
    __shared__ u8 xs[5 * 10816];
    __shared__ float part[10][320];
    const int tid = threadIdx.x, bid = blockIdx.x;
    const int s = bid & 7, rr_ = bid >> 3, b = rr_ >> 1, half = rr_ & 1;
    const int l = tid & 63, wvi = tid >> 6;
    const int wm = wvi >> 2, wn = wvi & 3;
    const int q = l >> 4, r16 = l & 15;

    const u8* gp[5];
#pragma unroll
    for (int nt = 0; nt < 5; ++nt) {
        int c = wn * 80 + nt * 16 + r16;
        gp[nt] = wpack3 + (size_t)s * 481280 + c * 32 + q * 8;
    }

    u64 bf0[5], bf1[5];
#pragma unroll
    for (int nt = 0; nt < 5; ++nt) bf0[nt] = *reinterpret_cast<const u64*>(gp[nt]);
#pragma unroll
    for (int nt = 0; nt < 5; ++nt) bf1[nt] = *reinterpret_cast<const u64*>(gp[nt] + 10240);

    {
        const float4* xg = reinterpret_cast<const float4*>(
            news + (size_t)((b * 8 + s) * 10 + half * 5) * 9600);
        for (int base = 0; base < 12000; base += 4096) {
            float4 v[8];
#pragma unroll
            for (int j = 0; j < 8; ++j) {
                int idx = base + j * 512 + tid;
                if (idx < 12000) v[j] = xg[idx];
            }
#pragma unroll
            for (int j = 0; j < 8; ++j) {
                int idx = base + j * 512 + tid;
                if (idx < 12000) {
                    int day = idx / 2400, rem = idx - day * 2400;
                    u32 o = (u32)f2fp8(v[j].x) | ((u32)f2fp8(v[j].y) << 8)
                          | ((u32)f2fp8(v[j].z) << 16) | ((u32)f2fp8(v[j].w) << 24);
                    *reinterpret_cast<u32*>(&xs[day * 10816 + rem * 4]) = o;
                }
            }
        }
        for (int i = tid; i < 1520; i += 512) {
            int day = i / 304, p = i - day * 304;
            *reinterpret_cast<u32*>(&xs[day * 10816 + 9600 + p * 4]) = 0u;
        }
    }
    __syncthreads();

    f32x4 acc[5][5];
#pragma unroll
    for (int mt = 0; mt < 5; ++mt)
#pragma unroll
        for (int nt = 0; nt < 5; ++nt) acc[mt][nt] = (f32x4)(0.f);

#define LOADA(dst, ks) do {                                                       \
    _Pragma("unroll")                                                             \
    for (int mt_ = 0; mt_ < 5; ++mt_) {                                           \
        int di_ = wm * 5 + mt_;                                                   \
        int off_ = (di_ >> 1) * 10816 + (((di_ & 1) << 4) + r16) * 300            \
                   + (ks) * 32 + q * 8;                                           \
        u32 lo_ = *reinterpret_cast<const u32*>(&xs[off_]);                       \
        u32 hi_ = *reinterpret_cast<const u32*>(&xs[off_ + 4]);                   \
        dst[mt_] = (u64)lo_ | ((u64)hi_ << 32);                                   \
    } } while (0)

#define MFMAS(bfv, av) do {                                                       \
    _Pragma("unroll")                                                             \
    for (int nt_ = 0; nt_ < 5; ++nt_)                                             \
        _Pragma("unroll")                                                         \
        for (int mt_ = 0; mt_ < 5; ++mt_)                                         \
            acc[mt_][nt_] = __builtin_amdgcn_mfma_f32_16x16x32_fp8_fp8(          \
                (long long)av[mt_], (long long)bfv[nt_], acc[mt_][nt_], 0, 0, 0); \
    } while (0)

    for (int ks = 0; ks < 46; ks += 2) {
        u64 a0[5], a1[5];
        LOADA(a0, ks);
        MFMAS(bf0, a0);
#pragma unroll
        for (int nt = 0; nt < 5; ++nt)
            bf0[nt] = *reinterpret_cast<const u64*>(gp[nt] + (ks + 2) * 10240);

        LOADA(a1, ks + 1);
        MFMAS(bf1, a1);
        if (ks + 3 < 47) {
#pragma unroll
            for (int nt = 0; nt < 5; ++nt)
                bf1[nt] = *reinterpret_cast<const u64*>(gp[nt] + (ks + 3) * 10240);
        }
    }
    {
        u64 a0[5];
        LOADA(a0, 46);
        MFMAS(bf0, a0);
    }
#undef LOADA
#undef MFMAS

#pragma unroll
    for (int mt = 0; mt < 5; ++mt) {
        const int di = wm * 5 + mt;
        const int nwb = (di & 1) << 4;
#pragma unroll
        for (int nt = 0; nt < 5; ++nt) {
            int oc = wn * 80 + nt * 16 + r16;
            int L = (oc < 100) ? 30 : (oc < 200) ? 29 : 28;
            float mx = -3e38f;
#pragma unroll
            for (int rr = 0; rr < 4; ++rr) {
                int nw = nwb + q * 4 + rr;
                if (nw < L) mx = fmaxf(mx, acc[mt][nt][rr]);
            }
            mx = fmaxf(mx, __shfl_xor(mx, 16));
            mx = fmaxf(mx, __shfl_xor(mx, 32));
            if (l < 16) part[di][wn * 80 + nt * 16 + l] = mx;
        }
    }
    __syncthreads();
    for (int i = tid; i < 1600; i += 512) {
        int day = i / 320, oc = i - day * 320;
        float mx = fmaxf(part[2 * day][oc], part[2 * day + 1][oc]);
        text_bf[((size_t)(s * 16 + b) * 10 + half * 5 + day) * 320 + oc] =
            f2bf(mx * 0.0625f + bcomb[s * 320 + oc]);
    }
}

// ---------------------------------------------------------------------------
// lstm_pre v2: 320 blocks = (s,d,gq). Each block: pre[16b][128g] for
// g in [gq*128, gq*128+128). 4 waves x 2 n-tiles. B traffic 80KB/block
// (4x less than v1), 4x more blocks -> latency hidden by TLP.
// ---------------------------------------------------------------------------
__global__ __launch_bounds__(256) void lstm_pre_mfma(const u16* __restrict__ text_bf,
                                                     const u16* __restrict__ wpre2,
                                                     const float* __restrict__ b_ih,
                                                     const float* __restrict__ b_hh,
                                                     float* __restrict__ pre) {
    __shared__ u16 as16[16 * 320];
    const int blk = blockIdx.x;
    const int gq = blk & 3, sd = blk >> 2, s = sd / 10, d = sd % 10;
    const int tid = threadIdx.x, l = tid & 63, w = tid >> 6, q = l >> 4, r16 = l & 15;

    for (int i = tid; i < 640; i += 256) {
        int r = i / 40, c = i % 40;
        *reinterpret_cast<float4*>(as16 + r * 320 + ((c ^ (r & 7)) << 3)) =
            *reinterpret_cast<const float4*>(text_bf + ((size_t)(s * 16 + r) * 10 + d) * 320 + c * 8);
    }
    __syncthreads();

    const u16* gpb[2];
#pragma unroll
    for (int nt = 0; nt < 2; ++nt) {
        int g = gq * 128 + w * 32 + nt * 16 + r16;
        gpb[nt] = wpre2 + (size_t)s * 163840 + g * 32 + q * 8;
    }

    f32x4 acc[2];
#pragma unroll
    for (int nt = 0; nt < 2; ++nt) acc[nt] = (f32x4)(0.f);

    for (int ks = 0; ks < 10; ++ks) {
        short8 a = *reinterpret_cast<const short8*>(
            as16 + r16 * 320 + (((ks * 4 + q) ^ (r16 & 7)) << 3));
#pragma unroll
        for (int nt = 0; nt < 2; ++nt) {
            short8 bf = *reinterpret_cast<const short8*>(gpb[nt] + ks * 16384);
            acc[nt] = __builtin_amdgcn_mfma_f32_16x16x32_bf16(a, bf, acc[nt], 0, 0, 0);
        }
    }

#pragma unroll
    for (int nt = 0; nt < 2; ++nt) {
        int g = gq * 128 + w * 32 + nt * 16 + r16;
        float bias = b_ih[s * G4_ + g] + b_hh[s * G4_ + g];
#pragma unroll
        for (int r = 0; r < 4; ++r) {
            int brow = q * 4 + r;
            pre[((size_t)sd * 16 + brow) * 512 + g] = acc[nt][r] + bias;
        }
    }
}

// ---------------------------------------------------------------------------
// stock_tail v3 (unchanged from R16)
// ---------------------------------------------------------------------------
__global__ __launch_bounds__(512, 1) void stock_tail(const float* __restrict__ pre,
                                                     const u16* __restrict__ whh_pk,
                                                     const u16* __restrict__ lxw_pk,
                                                     const u16* __restrict__ lyw_pk,
                                                     const float* __restrict__ lxb,
                                                     const float* __restrict__ lyb,
                                                     float* __restrict__ total) {
    __shared__ float gates[16 * GP_];
    __shared__ u16 hA[16 * 128];
    __shared__ u16 combA[16 * 256];
    __shared__ u16 hxA[16 * 128];
    const int s = blockIdx.x;
    const int t = threadIdx.x, l = t & 63, wv = t >> 6, q = l >> 4, r16 = l & 15;

    short8 ghr[4][4];
#pragma unroll
    for (int ks2 = 0; ks2 < 4; ++ks2)
#pragma unroll
        for (int nt = 0; nt < 4; ++nt) {
            int g = wv * 64 + nt * 16 + r16;
            ghr[ks2][nt] = *reinterpret_cast<const short8*>(
                whh_pk + (size_t)s * 65536 + ks2 * 16384 + g * 32 + q * 8);
        }

    reinterpret_cast<u64*>(hA)[t] = 0ull;
    float cst[4] = {0.f, 0.f, 0.f, 0.f};
    float hsum[4] = {0.f, 0.f, 0.f, 0.f};

    float pc[16], pn[16];
#pragma unroll
    for (int k = 0; k < 4; ++k) {
        int p = t + 512 * k; int b = p >> 7, h = p & 127;
        const float* base = pre + ((size_t)((s * 10 + 0) * 16 + b)) * 512 + h;
#pragma unroll
        for (int g = 0; g < 4; ++g) pc[k * 4 + g] = base[g * 128];
    }
    __syncthreads();

    for (int d = 0; d < D_; ++d) {
        f32x4 acc[4];
#pragma unroll
        for (int nt = 0; nt < 4; ++nt) acc[nt] = (f32x4)(0.f);
#pragma unroll
        for (int ks2 = 0; ks2 < 4; ++ks2) {
            int gran = (ks2 * 4 + q) ^ (r16 & 7);
            short8 ah = *reinterpret_cast<const short8*>(&hA[r16 * 128 + gran * 8]);
#pragma unroll
            for (int nt = 0; nt < 4; ++nt)
                acc[nt] = __builtin_amdgcn_mfma_f32_16x16x32_bf16(ah, ghr[ks2][nt], acc[nt], 0, 0, 0);
        }
        if (d + 1 < D_) {
#pragma unroll
            for (int k = 0; k < 4; ++k) {
                int p = t + 512 * k; int b = p >> 7, h = p & 127;
                const float* base = pre + ((size_t)((s * 10 + d + 1) * 16 + b)) * 512 + h;
#pragma unroll
                for (int g = 0; g < 4; ++g) pn[k * 4 + g] = base[g * 128];
            }
        }
        __syncthreads();
#pragma unroll
        for (int nt = 0; nt < 4; ++nt) {
            int g = wv * 64 + nt * 16 + r16;
#pragma unroll
            for (int rr = 0; rr < 4; ++rr)
                gates[(q * 4 + rr) * GP_ + g] = acc[nt][rr];
        }
        __syncthreads();
#pragma unroll
        for (int k = 0; k < 4; ++k) {
            int p = t + 512 * k;
            int b = p >> 7, h = p & 127;
            float ig = 1.f / (1.f + expf(-(pc[k*4+0] + gates[b * GP_ + h])));
            float fg = 1.f / (1.f + expf(-(pc[k*4+1] + gates[b * GP_ + 128 + h])));
            float gg = tanhf(pc[k*4+2] + gates[b * GP_ + 256 + h]);
            float og = 1.f / (1.f + expf(-(pc[k*4+3] + gates[b * GP_ + 384 + h])));
            float c = fg * cst[k] + ig * gg;
            cst[k] = c;
            float hv = og * tanhf(c);
            hsum[k] += hv;
            hA[b * 128 + (((h >> 3) ^ (b & 7)) << 3) + (h & 7)] = f2bf(hv);
            if (d == D_ - 1) {
                combA[b * 256 + (((h >> 3) ^ (b & 7)) << 3) + (h & 7)] = f2bf(hv);
                combA[b * 256 + ((((128 + h) >> 3) ^ (b & 7)) << 3) + (h & 7)] = f2bf(hsum[k]);
            }
        }
#pragma unroll
        for (int i = 0; i < 16; ++i) pc[i] = pn[i];
        __syncthreads();
    }

    {
        int col = wv * 16 + r16;
        f32x4 xacc = (f32x4)(lxb[s * H_ + col]);
#pragma unroll
        for (int ks = 0; ks < 8; ++ks) {
            int gran = (ks * 4 + q) ^ (r16 & 7);
            short8 a = *reinterpret_cast<const short8*>(&combA[r16 * 256 + gran * 8]);
            short8 bfr = *reinterpret_cast<const short8*>(
                lxw_pk + (size_t)s * 32768 + ks * 4096 + col * 32 + q * 8);
            xacc = __builtin_amdgcn_mfma_f32_16x16x32_bf16(a, bfr, xacc, 0, 0, 0);
        }
#pragma unroll
        for (int rr = 0; rr < 4; ++rr) {
            int b = q * 4 + rr;
            float v = fmaxf(xacc[rr], 0.f);
            hxA[b * 128 + (((col >> 3) ^ (b & 7)) << 3) + (col & 7)] = f2bf(v);
        }
    }
    __syncthreads();

    if (wv < 4) {
        int col = wv * 16 + r16;
        f32x4 yacc = (f32x4)(lyb[s * 64 + col]);
#pragma unroll
        for (int ks = 0; ks < 4; ++ks) {
            int gran = (ks * 4 + q) ^ (r16 & 7);
            short8 a = *reinterpret_cast<const short8*>(&hxA[r16 * 128 + gran * 8]);
            short8 bfr = *reinterpret_cast<const short8*>(
                lyw_pk + (size_t)s * 8192 + ks * 2048 + col * 32 + q * 8);
            yacc = __builtin_amdgcn_mfma_f32_16x16x32_bf16(a, bfr, yacc, 0, 0, 0);
        }
#pragma unroll
        for (int rr = 0; rr < 4; ++rr) {
            int b = q * 4 + rr;
            total[(size_t)b * 512 + s * 64 + col] = fmaxf(yacc[rr], 0.f);
        }
    }
}

// ---------------------------------------------------------------------------
// head_feats (unchanged)
// ---------------------------------------------------------------------------
__global__ __launch_bounds__(512) void head_feats(const float* __restrict__ total,
                                                  const float* __restrict__ sf,
                                                  const float* __restrict__ w1, const float* __restrict__ b1,
                                                  const float* __restrict__ w2, const float* __restrict__ b2,
                                                  const float* __restrict__ aw1T, const float* __restrict__ ab1,
                                                  const float* __restrict__ aw2, const float* __restrict__ ab2,
                                                  const float* __restrict__ avar,
                                                  float* __restrict__ out) {
    __shared__ __align__(16) float tr[TOT_];
    __shared__ float hid[MID_];
    __shared__ float h1f[24];
    __shared__ float pA[MID_], pB[MID_];
    const int bb = blockIdx.x, t = threadIdx.x;
    if (t < 128)
        reinterpret_cast<float4*>(tr)[t] = reinterpret_cast<const float4*>(total + (size_t)bb * 512)[t];
    if (t < 24) {
        float acc = b1[t];
        for (int i = 0; i < SDIM_; ++i) acc = fmaf(sf[bb * SDIM_ + i], w1[t * SDIM_ + i], acc);
        h1f[t] = fmaxf(acc, 0.f);
    }
    __syncthreads();
    if (t < 16) {
        float acc = b2[t];
        for (int i = 0; i < 24; ++i) acc = fmaf(h1f[i], w2[t * 24 + i], acc);
        tr[512 + t] = acc;
    }
    __syncthreads();
    {
        const int j = t & 255, hf = t >> 8;
        const int ilo = hf ? 264 : 0, ihi = hf ? 528 : 264;
        const float* wv = aw1T + j;
        float a0 = 0.f, a1 = 0.f, a2 = 0.f, a3 = 0.f;
        for (int i = ilo; i < ihi; i += 4) {
            a0 = fmaf(tr[i + 0], wv[(size_t)(i + 0) * 256], a0);
            a1 = fmaf(tr[i + 1], wv[(size_t)(i + 1) * 256], a1);
            a2 = fmaf(tr[i + 2], wv[(size_t)(i + 2) * 256], a2);
            a3 = fmaf(tr[i + 3], wv[(size_t)(i + 3) * 256], a3);
        }
        float p = (a0 + a1) + (a2 + a3);
        if (hf) pB[j] = p; else pA[j] = p;
    }
    __syncthreads();
    if (t < MID_) hid[t] = fmaxf(pA[t] + pB[t] + ab1[t], 0.f);
    __syncthreads();
    if (t < 8) {
        float acc = ab2[t];
        const float* wv = aw2 + (size_t)t * MID_;
        for (int i = 0; i < MID_; ++i) acc = fmaf(hid[i], wv[i], acc);
        out[bb * 8 + t] = tanhf(acc);
    }
    if (bb == 0 && t >= 8 && t < 16) out[128 + (t - 8)] = expf(avar[t - 8]);
}

// ---------------------------------------------------------------------------
extern "C" void kernel_launch(void* const* d_in, const int* in_sizes, int n_in,
                              void* d_out, int out_size, void* d_ws, size_t ws_size,
                              hipStream_t stream) {
    const float* news = (const float*)d_in[0];
    const float* sf   = (const float*)d_in[1];
    const float* w3   = (const float*)d_in[2];  const float* b3 = (const float*)d_in[3];
    const float* w4   = (const float*)d_in[4];  const float* b4 = (const float*)d_in[5];
    const float* w5   = (const float*)d_in[6];  const float* b5 = (const float*)d_in[7];
    const float* w_ih = (const float*)d_in[8];  const float* w_hh = (const float*)d_in[9];
    const float* b_ih = (const float*)d_in[10]; const float* b_hh = (const float*)d_in[11];
    const float* lxw  = (const float*)d_in[12]; const float* lxb = (const float*)d_in[13];
    const float* lyw  = (const float*)d_in[14]; const float* lyb = (const float*)d_in[15];
    const float* w1   = (const float*)d_in[16]; const float* b1 = (const float*)d_in[17];
    const float* w2   = (const float*)d_in[18]; const float* b2 = (const float*)d_in[19];
    const float* aw1  = (const float*)d_in[20]; const float* ab1 = (const float*)d_in[21];
    const float* aw2  = (const float*)d_in[22]; const float* ab2 = (const float*)d_in[23];
    const float* avar = (const float*)d_in[24];

    char* ws = (char*)d_ws;
    u8*    wpack3  = (u8*)ws;                                   // 3,850,240 B
    u16*   wpre2   = (u16*)(ws + 3850240);                      // 2,621,440 B
    u16*   whh_pk  = (u16*)(ws + 6471680);                      // 1,048,576 B
    u16*   lxw_pk  = (u16*)(ws + 7520256);                      //   524,288 B
    u16*   lyw_pk  = (u16*)(ws + 8044544);                      //   131,072 B
    float* bcomb   = (float*)(ws + 8175616);                    //    10,240 B
    u16*   text_bf = (u16*)(ws + 8185856);                      //   819,200 B
    float* total   = (float*)(ws + 9005056);                    //    32,768 B
    float* aw1T    = (float*)(ws + 9037824);                    //   540,672 B
    float* pre     = (float*)(ws + 9578496);                    // 2,621,440 B (end ~12.2 MB)

    prep<<<1385, 256, 0, stream>>>(w3, b3, w4, b4, w5, b5, w_ih, w_hh, lxw, lyw, aw1,
                                   wpack3, wpre2, whh_pk, lxw_pk, lyw_pk, bcomb, aw1T);
    conv_mfma<<<256, 512, 0, stream>>>(news, wpack3, bcomb, text_bf);
    lstm_pre_mfma<<<320, 256, 0, stream>>>(text_bf, wpre2, b_ih, b_hh, pre);
    stock_tail<<<S_, 512, 0, stream>>>(pre, whh_pk, lxw_pk, lyw_pk, lxb, lyb, total);
    head_feats<<<B_, 512, 0, stream>>>(total, sf, w1, b1, w2, b2, aw1T, ab1, aw2, ab2, avar, (float*)d_out);
}